// Round 8
// baseline (99.833 us; speedup 1.0000x reference)
//
#include <hip/hip_runtime.h>

// ---- problem constants ----
#define HOP 160
#define NROWS 402
#define NTAPS 400
#define T_SIG 9600000
#define N_FRAMES 60001
#define PAD 200

typedef __bf16 bf16x8 __attribute__((ext_vector_type(8)));
typedef float f32x16 __attribute__((ext_vector_type(16)));
typedef unsigned short u16x8 __attribute__((ext_vector_type(8)));
typedef unsigned short u16x4 __attribute__((ext_vector_type(4)));
typedef unsigned int u32x4 __attribute__((ext_vector_type(4)));

__device__ __forceinline__ unsigned short f2bf(float f) {
    unsigned int u = __builtin_bit_cast(unsigned int, f);
    u += 0x7fffu + ((u >> 16) & 1u);
    return (unsigned short)(u >> 16);
}

__device__ __forceinline__ void gll16(const void* g, void* l) {
    __builtin_amdgcn_global_load_lds(
        (const __attribute__((address_space(1))) unsigned int*)g,
        (__attribute__((address_space(3))) unsigned int*)l, 16, 0, 0);
}

// ================= TIER 1: GEMM-structured, 3 blocks/CU =================
// C[row][t] = sum_k basis[row][k] * sig[t*160 + k - 200]
// ws layout: Apack (425984 B) | sigbf padded (20172800 B)
// Apack: [bm][phase p=0..12][slot s=0..511] of 16B frags:
//   r=s>>2, q=s&3, ka=2p+(q>>1), g=q&1 -> bf16 basis[bm*128+r][ka*16+g*8 .. +8)
// sigbf: bf16, shifted +200, +8 elems per 160 -> window bt = 43552 B @ bt*43008.

#define SIG_OFF 425984
#define ABM_STRIDE 106496        // 13 phases * 8192 B
#define SIG_LDS_B 43552          // 21776 elems (2722 16B slots)
#define A_LDS_B 9216             // 128 rows * 72 B (64 data + 8 pad)
#define NEED1 (425984UL + 20172800UL)

// prep: fp32 signal -> padded bf16 array (covers i in [0, 9605760))
__global__ void prep_sig(const float* __restrict__ sig,
                         unsigned short* __restrict__ sp) {
    long chunk = (long)blockIdx.x * 256 + threadIdx.x;
    if (chunk >= 2401440L) return;
    long i = chunk * 4;
    long pos = i + 8 * (i / 160);   // 4-chunk never crosses a 160-boundary
    u16x4 v;
    if (i >= 200 && i + 4 <= 9600200L) {
        float4 f = *reinterpret_cast<const float4*>(sig + (i - 200));
        v[0] = f2bf(f.x); v[1] = f2bf(f.y); v[2] = f2bf(f.z); v[3] = f2bf(f.w);
    } else {
        v[0] = v[1] = v[2] = v[3] = 0;
    }
    *reinterpret_cast<u16x4*>(sp + pos) = v;
}

// prep: basis fp32 -> Apack (26624 slots of 16B)
__global__ void prep_a(const float* __restrict__ basis,
                       unsigned short* __restrict__ ap) {
    int s = blockIdx.x * 256 + threadIdx.x;   // 104*256 = 26624 exactly
    int bm = s / 6656, rem = s % 6656;
    int p = rem >> 9, s2 = rem & 511;
    int r = s2 >> 2, q = s2 & 3;
    int ka = 2 * p + (q >> 1);
    int k0 = ka * 16 + (q & 1) * 8;
    int m = bm * 128 + r;
    u16x8 v;
#pragma unroll
    for (int j = 0; j < 8; ++j) {
        int k = k0 + j;
        float f = (m < NROWS && k < NTAPS) ? basis[m * NTAPS + k] : 0.0f;
        v[j] = f2bf(f);
    }
    *reinterpret_cast<u16x8*>(ap + (size_t)s * 8) = v;
}

#define STORE_ACC(A, R0, T) do { if ((T) < (long)N_FRAMES) { _Pragma("unroll") \
    for (int r = 0; r < 16; ++r) { \
        int row = (R0) + (r & 3) + 8 * (r >> 2); \
        if (row < NROWS) out[(long)row * N_FRAMES + (T)] = (A)[r]; \
    } } } while (0)

__launch_bounds__(256)
__global__ void stft_gemm(const unsigned short* __restrict__ sigp,
                          const unsigned short* __restrict__ apack,
                          float* __restrict__ out) {
    __shared__ __align__(16) char lds[SIG_LDS_B + A_LDS_B];  // 52768 B -> 3 blocks/CU
    char* sB = lds;
    char* aB = lds + SIG_LDS_B;
    const int tid = threadIdx.x;
    const int bt = blockIdx.x % 469;        // bt fastest: neighbors share Apack (L2)
    const int bm = blockIdx.x / 469;
    const char* aBase = (const char*)apack + (size_t)bm * ABM_STRIDE;

    // prologue: A phase-0 loads, sig window gll, A write, barrier
    u32x4 areg0, areg1;
    areg0 = *reinterpret_cast<const u32x4*>(aBase + (size_t)tid * 16);
    areg1 = *reinterpret_cast<const u32x4*>(aBase + (size_t)(256 + tid) * 16);
    {
        const char* sg = (const char*)sigp + (size_t)bt * 43008;
#pragma unroll
        for (int it = 0; it < 11; ++it) {
            int slot = it * 256 + tid;      // 2722 slots
            if (slot < 2722) gll16(sg + slot * 16, sB + slot * 16);
        }
    }
    {
        int s0 = tid, s1 = 256 + tid;
        *reinterpret_cast<u32x4*>(aB + (s0 >> 2) * 72 + (s0 & 3) * 16) = areg0;
        *reinterpret_cast<u32x4*>(aB + (s1 >> 2) * 72 + (s1 & 3) * 16) = areg1;
    }
    __syncthreads();

    const int lane = tid & 63;
    const int w = tid >> 6;
    const int wm = w >> 1;                  // 64-row half
    const int wf = w & 1;                   // 64-frame half
    const int l31 = lane & 31;
    const int g = lane >> 5;

    const char* aR = aB + (wm * 64 + l31) * 72 + g * 16;   // +kl*32; +2304 row+32
    const char* sB0 = sB + (wf * 64 + l31) * 336 + g * 16; // +sc;   +10752 col+32

    f32x16 acc00 = {0,0,0,0,0,0,0,0,0,0,0,0,0,0,0,0};
    f32x16 acc01 = {0,0,0,0,0,0,0,0,0,0,0,0,0,0,0,0};
    f32x16 acc10 = {0,0,0,0,0,0,0,0,0,0,0,0,0,0,0,0};
    f32x16 acc11 = {0,0,0,0,0,0,0,0,0,0,0,0,0,0,0,0};

    // 13 phases x 2 ka: prefetch next A chunk, compute current, swap via 2 barriers
#pragma unroll
    for (int p = 0; p < 13; ++p) {
        if (p < 12) {
            const char* nb = aBase + (size_t)(p + 1) * 8192;
            areg0 = *reinterpret_cast<const u32x4*>(nb + (size_t)tid * 16);
            areg1 = *reinterpret_cast<const u32x4*>(nb + (size_t)(256 + tid) * 16);
        }
#pragma unroll
        for (int kl = 0; kl < 2; ++kl) {
            const int ka = 2 * p + kl;
            const int sc = ka * 32 + (ka >= 10 ? 16 : 0) + (ka >= 20 ? 16 : 0);
            bf16x8 a0 = *reinterpret_cast<const bf16x8*>(aR + kl * 32);
            bf16x8 a1 = *reinterpret_cast<const bf16x8*>(aR + 2304 + kl * 32);
            bf16x8 b0 = *reinterpret_cast<const bf16x8*>(sB0 + sc);
            bf16x8 b1 = *reinterpret_cast<const bf16x8*>(sB0 + 10752 + sc);
            acc00 = __builtin_amdgcn_mfma_f32_32x32x16_bf16(a0, b0, acc00, 0, 0, 0);
            acc01 = __builtin_amdgcn_mfma_f32_32x32x16_bf16(a0, b1, acc01, 0, 0, 0);
            acc10 = __builtin_amdgcn_mfma_f32_32x32x16_bf16(a1, b0, acc10, 0, 0, 0);
            acc11 = __builtin_amdgcn_mfma_f32_32x32x16_bf16(a1, b1, acc11, 0, 0, 0);
        }
        __syncthreads();                     // all waves done reading A buf
        if (p < 12) {
            int s0 = tid, s1 = 256 + tid;
            *reinterpret_cast<u32x4*>(aB + (s0 >> 2) * 72 + (s0 & 3) * 16) = areg0;
            *reinterpret_cast<u32x4*>(aB + (s1 >> 2) * 72 + (s1 & 3) * 16) = areg1;
            __syncthreads();                 // A buf now holds phase p+1
        }
    }

    const int rBase = bm * 128 + wm * 64 + 4 * g;
    const long tBase = (long)bt * 128 + wf * 64 + l31;
    STORE_ACC(acc00, rBase, tBase);
    STORE_ACC(acc01, rBase, tBase + 32);
    STORE_ACC(acc10, rBase + 32, tBase);
    STORE_ACC(acc11, rBase + 32, tBase + 32);
}

// ================= TIER 2: R3 fallback (proven 65-73 us) =================
#define MT 13
#define KS 26
#define FPB 128
#define MSPLIT 3
#define NBT ((N_FRAMES + FPB - 1) / FPB)
#define SPAN (127*HOP + 416)
#define SPAN4 (SPAN/4)
#define LDSE 21776

__global__ void stft_prep2(const float* __restrict__ basis,
                           unsigned short* __restrict__ packed) {
    int tid = blockIdx.x * 256 + threadIdx.x;
    if (tid >= MT * KS * 64) return;
    int lane = tid & 63;
    int frag = tid >> 6;
    int ks = frag % KS;
    int mt = frag / KS;
    int row = mt * 32 + (lane & 31);
    int colb = ks * 16 + (lane >> 5) * 8;
    u16x8 v;
#pragma unroll
    for (int i = 0; i < 8; ++i) {
        int col = colb + i;
        float f = (row < NROWS && col < NTAPS) ? basis[row * NTAPS + col] : 0.0f;
        v[i] = f2bf(f);
    }
    *reinterpret_cast<u16x8*>(packed + (size_t)tid * 8) = v;
}

__launch_bounds__(256, 3)
__global__ void stft_mfma2(const float* __restrict__ sig,
                           const unsigned short* __restrict__ packedA,
                           float* __restrict__ out) {
    __shared__ unsigned short sl[LDSE];
    const int tid = threadIdx.x;
    const int bt = blockIdx.x % NBT;
    const int bmm = blockIdx.x / NBT;
    const long sbase = (long)bt * (FPB * HOP) - PAD;
    for (int idx = tid; idx < SPAN4; idx += 256) {
        const int e = idx * 4;
        const long g0 = sbase + e;
        float4 v;
        if (g0 >= 0 && g0 + 4 <= (long)T_SIG) {
            v = *reinterpret_cast<const float4*>(sig + g0);
        } else {
            v.x = (g0 + 0 >= 0 && g0 + 0 < (long)T_SIG) ? sig[g0 + 0] : 0.0f;
            v.y = (g0 + 1 >= 0 && g0 + 1 < (long)T_SIG) ? sig[g0 + 1] : 0.0f;
            v.z = (g0 + 2 >= 0 && g0 + 2 < (long)T_SIG) ? sig[g0 + 2] : 0.0f;
            v.w = (g0 + 3 >= 0 && g0 + 3 < (long)T_SIG) ? sig[g0 + 3] : 0.0f;
        }
        u16x4 s;
        s[0] = f2bf(v.x); s[1] = f2bf(v.y); s[2] = f2bf(v.z); s[3] = f2bf(v.w);
        const int pos = e + 8 * (e / 160);
        *reinterpret_cast<u16x4*>(&sl[pos]) = s;
    }
    __syncthreads();
    const int lane = tid & 63;
    const int w = tid >> 6;
    const int l31 = lane & 31;
    const int g = lane >> 5;
    const int lf = w * 32 + l31;
    const long t = (long)bt * FPB + lf;
    const int mt0 = (bmm == 0) ? 0 : 5 + 4 * (bmm - 1);
    const int mtN = (bmm == 0) ? 5 : 4;
    const unsigned short* bbase = &sl[lf * 168 + g * 8];
    const int rowg = 4 * g;
#pragma unroll 1
    for (int mi = 0; mi < mtN; ++mi) {
        const int mt = mt0 + mi;
        f32x16 acc = {0,0,0,0,0,0,0,0,0,0,0,0,0,0,0,0};
        const unsigned short* pA = packedA + ((size_t)(mt * KS) * 64 + lane) * 8;
#pragma unroll
        for (int ks = 0; ks < KS; ++ks) {
            const bf16x8 a = *reinterpret_cast<const bf16x8*>(pA + (size_t)ks * 512);
            const bf16x8 b = *reinterpret_cast<const bf16x8*>(bbase + ks * 16 + 8 * (ks / 10));
            acc = __builtin_amdgcn_mfma_f32_32x32x16_bf16(a, b, acc, 0, 0, 0);
        }
        if (t < N_FRAMES) {
            const int rb = mt * 32 + rowg;
#pragma unroll
            for (int r = 0; r < 16; ++r) {
                const int row = rb + (r & 3) + 8 * (r >> 2);
                if (row < NROWS) out[(long)row * N_FRAMES + t] = acc[r];
            }
        }
        __syncthreads();
    }
}

// ================= TIER 3: naive =================
__global__ void stft_naive(const float* __restrict__ sig,
                           const float* __restrict__ basis,
                           float* __restrict__ out) {
    long idx = (long)blockIdx.x * 256 + threadIdx.x;
    if (idx >= (long)NROWS * N_FRAMES) return;
    int row = (int)(idx / N_FRAMES);
    int tt = (int)(idx % N_FRAMES);
    long s0 = (long)tt * HOP - PAD;
    float acc = 0.0f;
    for (int n = 0; n < NTAPS; ++n) {
        long s = s0 + n;
        float x = (s >= 0 && s < (long)T_SIG) ? sig[s] : 0.0f;
        acc = fmaf(x, basis[row * NTAPS + n], acc);
    }
    out[idx] = acc;
}

extern "C" void kernel_launch(void* const* d_in, const int* in_sizes, int n_in,
                              void* d_out, int out_size, void* d_ws, size_t ws_size,
                              hipStream_t stream) {
    (void)in_sizes; (void)n_in; (void)out_size;
    const float* sig = (const float*)d_in[0];
    const float* basis = (const float*)d_in[1];
    float* out = (float*)d_out;
    if (ws_size >= NEED1) {
        unsigned short* ap = (unsigned short*)d_ws;
        unsigned short* sp = (unsigned short*)((char*)d_ws + SIG_OFF);
        prep_sig<<<9381, 256, 0, stream>>>(sig, sp);
        prep_a<<<104, 256, 0, stream>>>(basis, ap);
        stft_gemm<<<469 * 4, 256, 0, stream>>>(sp, ap, out);
    } else if (ws_size >= (size_t)MT * KS * 64 * 8 * sizeof(unsigned short)) {
        unsigned short* packed = (unsigned short*)d_ws;
        stft_prep2<<<(MT * KS * 64 + 255) / 256, 256, 0, stream>>>(basis, packed);
        stft_mfma2<<<NBT * MSPLIT, 256, 0, stream>>>(sig, packed, out);
    } else {
        long total = (long)NROWS * N_FRAMES;
        stft_naive<<<(int)((total + 255) / 256), 256, 0, stream>>>(sig, basis, out);
    }
}

// Round 9
// 73.015 us; speedup vs baseline: 1.3673x; 1.3673x over previous
//
#include <hip/hip_runtime.h>

// ---- problem constants ----
#define HOP 160
#define NROWS 402
#define NTAPS 400
#define T_SIG 9600000
#define N_FRAMES 60001
#define PAD 200

typedef __bf16 bf16x8 __attribute__((ext_vector_type(8)));
typedef float f32x16 __attribute__((ext_vector_type(16)));
typedef unsigned short u16x8 __attribute__((ext_vector_type(8)));
typedef unsigned short u16x4 __attribute__((ext_vector_type(4)));
typedef unsigned int u32x4 __attribute__((ext_vector_type(4)));

__device__ __forceinline__ unsigned short f2bf(float f) {
    unsigned int u = __builtin_bit_cast(unsigned int, f);
    u += 0x7fffu + ((u >> 16) & 1u);
    return (unsigned short)(u >> 16);
}

__device__ __forceinline__ void gll16(const void* g, void* l) {
    __builtin_amdgcn_global_load_lds(
        (const __attribute__((address_space(1))) unsigned int*)g,
        (__attribute__((address_space(3))) unsigned int*)l, 16, 0, 0);
}

// ================= TIER 1: barrier-free wave-private GEMM =================
// C[row][t] = sum_k basis[row][k] * sig[t*160 + k - 200]
// ws: Apack (425984 B) | sigbf padded (20172800 B)
// Apack: [bm2=0..7][ka=0..25][s2=0..127] 16B frags;
//   s2 -> r=s2>>1, g=s2&1; holds bf16 basis[bm2*64+r][ka*16+g*8 .. +8)  (0-pad)
// sigbf: bf16, shifted +200, +8 elems per 160 -> window bt = 43552 B @ bt*43008.
// Block: 128 rows x 128 frames, 4 waves (wm,wf) of 64x64. After ONE prologue
// barrier (sig gll), waves free-run: per ka-phase each wave streams its own
// 2KB A-chunk global->regs(2-slot prefetch)->private LDS->frags->4 MFMA.
// No __syncthreads in the K-loop (LDS ops per wave are in-order).

#define SIG_OFF 425984
#define SIG_LDS_B 43552          // 2722 16B slots
#define AW_LDS_B 2048            // per-wave A chunk: 64 rows x 16 taps bf16
#define NEED1 (425984UL + 20172800UL)

// prep: fp32 signal -> padded bf16 array (covers i in [0, 9605760))
__global__ void prep_sig(const float* __restrict__ sig,
                         unsigned short* __restrict__ sp) {
    long chunk = (long)blockIdx.x * 256 + threadIdx.x;
    if (chunk >= 2401440L) return;
    long i = chunk * 4;
    long pos = i + 8 * (i / 160);   // 4-chunk never crosses a 160-boundary
    u16x4 v;
    if (i >= 200 && i + 4 <= 9600200L) {
        float4 f = *reinterpret_cast<const float4*>(sig + (i - 200));
        v[0] = f2bf(f.x); v[1] = f2bf(f.y); v[2] = f2bf(f.z); v[3] = f2bf(f.w);
    } else {
        v[0] = v[1] = v[2] = v[3] = 0;
    }
    *reinterpret_cast<u16x4*>(sp + pos) = v;
}

// prep: basis fp32 -> Apack (26624 slots of 16B)
__global__ void prep_a(const float* __restrict__ basis,
                       unsigned short* __restrict__ ap) {
    int s = blockIdx.x * 256 + threadIdx.x;   // 104*256 = 26624 exactly
    int bm2 = s / 3328, rem = s % 3328;
    int ka = rem >> 7, s2 = rem & 127;
    int r = s2 >> 1, g = s2 & 1;
    int row = bm2 * 64 + r;
    int k0 = ka * 16 + g * 8;
    u16x8 v;
#pragma unroll
    for (int j = 0; j < 8; ++j) {
        int k = k0 + j;
        float f = (row < NROWS && k < NTAPS) ? basis[row * NTAPS + k] : 0.0f;
        v[j] = f2bf(f);
    }
    *reinterpret_cast<u16x8*>(ap + (size_t)s * 8) = v;
}

#define STORE_ACC(A, R0, T) do { if ((T) < (long)N_FRAMES) { _Pragma("unroll") \
    for (int r = 0; r < 16; ++r) { \
        int row = (R0) + (r & 3) + 8 * (r >> 2); \
        if (row < NROWS) out[(long)row * N_FRAMES + (T)] = (A)[r]; \
    } } } while (0)

__launch_bounds__(256, 3)
__global__ void stft_gemm(const unsigned short* __restrict__ sigp,
                          const unsigned short* __restrict__ apack,
                          float* __restrict__ out) {
    __shared__ __align__(16) char lds[SIG_LDS_B + 4 * AW_LDS_B]; // 51744 -> 3 blk/CU
    char* sB = lds;
    const int tid = threadIdx.x;
    const int bm = blockIdx.x & 3;          // bm fastest: neighbors share sig (R7-proven)
    const int bt = blockIdx.x >> 2;
    const int lane = tid & 63;
    const int w = tid >> 6;
    const int wm = w >> 1;                  // 64-row half
    const int wf = w & 1;                   // 64-frame half
    const int bm2 = bm * 2 + wm;            // wave's 64-row chunk (0..7)
    char* aw = lds + SIG_LDS_B + w * AW_LDS_B;   // wave-private A scratch
    const char* aBase = (const char*)apack + (size_t)bm2 * 53248;
    const int lo0 = lane * 16, lo1 = 1024 + lane * 16;

    // prologue: issue A slot0/slot1 loads, then sig gll; one barrier total
    u32x4 s0a = *reinterpret_cast<const u32x4*>(aBase + lo0);
    u32x4 s0b = *reinterpret_cast<const u32x4*>(aBase + lo1);
    u32x4 s1a = *reinterpret_cast<const u32x4*>(aBase + 2048 + lo0);
    u32x4 s1b = *reinterpret_cast<const u32x4*>(aBase + 2048 + lo1);
    {
        const char* sg = (const char*)sigp + (size_t)bt * 43008;
#pragma unroll
        for (int it = 0; it < 11; ++it) {
            int slot = it * 256 + tid;      // 2722 slots
            if (slot < 2722) gll16(sg + slot * 16, sB + slot * 16);
        }
    }
    __syncthreads();

    const int l31 = lane & 31;
    const int g = lane >> 5;
    const char* aR0 = aw + l31 * 32 + g * 16;            // row l31
    const char* aR1 = aw + 1024 + l31 * 32 + g * 16;     // row 32+l31
    const char* sB0 = sB + (wf * 64 + l31) * 336 + g * 16;

    f32x16 acc00 = {0,0,0,0,0,0,0,0,0,0,0,0,0,0,0,0};
    f32x16 acc01 = {0,0,0,0,0,0,0,0,0,0,0,0,0,0,0,0};
    f32x16 acc10 = {0,0,0,0,0,0,0,0,0,0,0,0,0,0,0,0};
    f32x16 acc11 = {0,0,0,0,0,0,0,0,0,0,0,0,0,0,0,0};

    // 26 barrier-free phases; 2-slot register prefetch (load p+2 during p)
#pragma unroll
    for (int p = 0; p < 26; ++p) {
        // write slot p -> private LDS (vmcnt auto-wait on that slot only)
        if (p & 1) {
            *reinterpret_cast<u32x4*>(aw + lane * 16) = s1a;
            *reinterpret_cast<u32x4*>(aw + 1024 + lane * 16) = s1b;
        } else {
            *reinterpret_cast<u32x4*>(aw + lane * 16) = s0a;
            *reinterpret_cast<u32x4*>(aw + 1024 + lane * 16) = s0b;
        }
        // refill the freed slot with phase p+2
        if (p + 2 < 26) {
            const char* nb = aBase + (size_t)(p + 2) * 2048;
            if (p & 1) {
                s1a = *reinterpret_cast<const u32x4*>(nb + lo0);
                s1b = *reinterpret_cast<const u32x4*>(nb + lo1);
            } else {
                s0a = *reinterpret_cast<const u32x4*>(nb + lo0);
                s0b = *reinterpret_cast<const u32x4*>(nb + lo1);
            }
        }
        // fragments (same-wave LDS: in-order, lgkmcnt only)
        bf16x8 a0 = *reinterpret_cast<const bf16x8*>(aR0);
        bf16x8 a1 = *reinterpret_cast<const bf16x8*>(aR1);
        const int sc = p * 32 + (p >= 10 ? 16 : 0) + (p >= 20 ? 16 : 0);
        bf16x8 b0 = *reinterpret_cast<const bf16x8*>(sB0 + sc);
        bf16x8 b1 = *reinterpret_cast<const bf16x8*>(sB0 + 10752 + sc);
        acc00 = __builtin_amdgcn_mfma_f32_32x32x16_bf16(a0, b0, acc00, 0, 0, 0);
        acc01 = __builtin_amdgcn_mfma_f32_32x32x16_bf16(a0, b1, acc01, 0, 0, 0);
        acc10 = __builtin_amdgcn_mfma_f32_32x32x16_bf16(a1, b0, acc10, 0, 0, 0);
        acc11 = __builtin_amdgcn_mfma_f32_32x32x16_bf16(a1, b1, acc11, 0, 0, 0);
    }

    const int rBase = bm2 * 64 + 4 * g;
    const long tBase = (long)bt * 128 + wf * 64 + l31;
    STORE_ACC(acc00, rBase, tBase);
    STORE_ACC(acc01, rBase, tBase + 32);
    STORE_ACC(acc10, rBase + 32, tBase);
    STORE_ACC(acc11, rBase + 32, tBase + 32);
}

// ================= TIER 2: R3 fallback (proven 65-73 us) =================
#define MT 13
#define KS 26
#define FPB 128
#define MSPLIT 3
#define NBT ((N_FRAMES + FPB - 1) / FPB)
#define SPAN (127*HOP + 416)
#define SPAN4 (SPAN/4)
#define LDSE 21776

__global__ void stft_prep2(const float* __restrict__ basis,
                           unsigned short* __restrict__ packed) {
    int tid = blockIdx.x * 256 + threadIdx.x;
    if (tid >= MT * KS * 64) return;
    int lane = tid & 63;
    int frag = tid >> 6;
    int ks = frag % KS;
    int mt = frag / KS;
    int row = mt * 32 + (lane & 31);
    int colb = ks * 16 + (lane >> 5) * 8;
    u16x8 v;
#pragma unroll
    for (int i = 0; i < 8; ++i) {
        int col = colb + i;
        float f = (row < NROWS && col < NTAPS) ? basis[row * NTAPS + col] : 0.0f;
        v[i] = f2bf(f);
    }
    *reinterpret_cast<u16x8*>(packed + (size_t)tid * 8) = v;
}

__launch_bounds__(256, 3)
__global__ void stft_mfma2(const float* __restrict__ sig,
                           const unsigned short* __restrict__ packedA,
                           float* __restrict__ out) {
    __shared__ unsigned short sl[LDSE];
    const int tid = threadIdx.x;
    const int bt = blockIdx.x % NBT;
    const int bmm = blockIdx.x / NBT;
    const long sbase = (long)bt * (FPB * HOP) - PAD;
    for (int idx = tid; idx < SPAN4; idx += 256) {
        const int e = idx * 4;
        const long g0 = sbase + e;
        float4 v;
        if (g0 >= 0 && g0 + 4 <= (long)T_SIG) {
            v = *reinterpret_cast<const float4*>(sig + g0);
        } else {
            v.x = (g0 + 0 >= 0 && g0 + 0 < (long)T_SIG) ? sig[g0 + 0] : 0.0f;
            v.y = (g0 + 1 >= 0 && g0 + 1 < (long)T_SIG) ? sig[g0 + 1] : 0.0f;
            v.z = (g0 + 2 >= 0 && g0 + 2 < (long)T_SIG) ? sig[g0 + 2] : 0.0f;
            v.w = (g0 + 3 >= 0 && g0 + 3 < (long)T_SIG) ? sig[g0 + 3] : 0.0f;
        }
        u16x4 s;
        s[0] = f2bf(v.x); s[1] = f2bf(v.y); s[2] = f2bf(v.z); s[3] = f2bf(v.w);
        const int pos = e + 8 * (e / 160);
        *reinterpret_cast<u16x4*>(&sl[pos]) = s;
    }
    __syncthreads();
    const int lane = tid & 63;
    const int w = tid >> 6;
    const int l31 = lane & 31;
    const int g = lane >> 5;
    const int lf = w * 32 + l31;
    const long t = (long)bt * FPB + lf;
    const int mt0 = (bmm == 0) ? 0 : 5 + 4 * (bmm - 1);
    const int mtN = (bmm == 0) ? 5 : 4;
    const unsigned short* bbase = &sl[lf * 168 + g * 8];
    const int rowg = 4 * g;
#pragma unroll 1
    for (int mi = 0; mi < mtN; ++mi) {
        const int mt = mt0 + mi;
        f32x16 acc = {0,0,0,0,0,0,0,0,0,0,0,0,0,0,0,0};
        const unsigned short* pA = packedA + ((size_t)(mt * KS) * 64 + lane) * 8;
#pragma unroll
        for (int ks = 0; ks < KS; ++ks) {
            const bf16x8 a = *reinterpret_cast<const bf16x8*>(pA + (size_t)ks * 512);
            const bf16x8 b = *reinterpret_cast<const bf16x8*>(bbase + ks * 16 + 8 * (ks / 10));
            acc = __builtin_amdgcn_mfma_f32_32x32x16_bf16(a, b, acc, 0, 0, 0);
        }
        if (t < N_FRAMES) {
            const int rb = mt * 32 + rowg;
#pragma unroll
            for (int r = 0; r < 16; ++r) {
                const int row = rb + (r & 3) + 8 * (r >> 2);
                if (row < NROWS) out[(long)row * N_FRAMES + t] = acc[r];
            }
        }
        __syncthreads();
    }
}

// ================= TIER 3: naive =================
__global__ void stft_naive(const float* __restrict__ sig,
                           const float* __restrict__ basis,
                           float* __restrict__ out) {
    long idx = (long)blockIdx.x * 256 + threadIdx.x;
    if (idx >= (long)NROWS * N_FRAMES) return;
    int row = (int)(idx / N_FRAMES);
    int tt = (int)(idx % N_FRAMES);
    long s0 = (long)tt * HOP - PAD;
    float acc = 0.0f;
    for (int n = 0; n < NTAPS; ++n) {
        long s = s0 + n;
        float x = (s >= 0 && s < (long)T_SIG) ? sig[s] : 0.0f;
        acc = fmaf(x, basis[row * NTAPS + n], acc);
    }
    out[idx] = acc;
}

extern "C" void kernel_launch(void* const* d_in, const int* in_sizes, int n_in,
                              void* d_out, int out_size, void* d_ws, size_t ws_size,
                              hipStream_t stream) {
    (void)in_sizes; (void)n_in; (void)out_size;
    const float* sig = (const float*)d_in[0];
    const float* basis = (const float*)d_in[1];
    float* out = (float*)d_out;
    if (ws_size >= NEED1) {
        unsigned short* ap = (unsigned short*)d_ws;
        unsigned short* sp = (unsigned short*)((char*)d_ws + SIG_OFF);
        prep_sig<<<9381, 256, 0, stream>>>(sig, sp);
        prep_a<<<104, 256, 0, stream>>>(basis, ap);
        stft_gemm<<<469 * 4, 256, 0, stream>>>(sp, ap, out);
    } else if (ws_size >= (size_t)MT * KS * 64 * 8 * sizeof(unsigned short)) {
        unsigned short* packed = (unsigned short*)d_ws;
        stft_prep2<<<(MT * KS * 64 + 255) / 256, 256, 0, stream>>>(basis, packed);
        stft_mfma2<<<NBT * MSPLIT, 256, 0, stream>>>(sig, packed, out);
    } else {
        long total = (long)NROWS * N_FRAMES;
        stft_naive<<<(int)((total + 255) / 256), 256, 0, stream>>>(sig, basis, out);
    }
}